// Round 4
// baseline (261.235 us; speedup 1.0000x reference)
//
#include <hip/hip_runtime.h>
#include <hip/hip_bf16.h>
#include <cmath>

#define NB 4
#define NM 32
#define DKc 256
#define DVc 32
#define NP 4096

using bf16x8 = __attribute__((ext_vector_type(8))) short;
using f32x4  = __attribute__((ext_vector_type(4))) float;
using f32x2  = __attribute__((ext_vector_type(2))) float;

__device__ __forceinline__ unsigned short f2bf(float f) {
    union { float f; unsigned u; } x; x.f = f;
    unsigned r = 0x7FFFu + ((x.u >> 16) & 1u);
    return (unsigned short)((x.u + r) >> 16);
}

// ---------------- k_prep: fc transpose (1024 blocks) + W transposes (32) + vproj (64) ----------------
__global__ __launch_bounds__(256) void k_prep(
    const float* __restrict__ fc, unsigned short* __restrict__ fcT,
    const float* __restrict__ Q, unsigned short* __restrict__ WTq,
    const float* __restrict__ K, unsigned short* __restrict__ WTk,
    const float* __restrict__ fm, const float* __restrict__ V, float* __restrict__ vproj) {
    int x = blockIdx.x;
    int t = threadIdx.x;
    if (x < 1056) {
        __shared__ float tile[64][65];
        const float* s; unsigned short* d; int R, C, r0, c0;
        if (x < 1024) {
            int bb = x >> 8, rest = x & 255;
            R = 256; C = 4096;
            r0 = (rest >> 6) * 64; c0 = (rest & 63) * 64;
            s = fc + (long)bb * 256 * 4096; d = fcT + (long)bb * 256 * 4096;
        } else {
            int i = x - 1024;
            int mat = i >> 4, idx = i & 15;
            R = 256; C = 256;
            r0 = (idx >> 2) * 64; c0 = (idx & 3) * 64;
            s = mat ? K : Q; d = mat ? WTk : WTq;
        }
        #pragma unroll
        for (int j = 0; j < 16; ++j) {
            int i = t + 256 * j;
            int r = i >> 6, c = i & 63;
            tile[r][c] = s[(long)(r0 + r) * C + c0 + c];
        }
        __syncthreads();
        #pragma unroll
        for (int j = 0; j < 8; ++j) {
            int i = t + 256 * j;
            int row = i >> 5;
            int pr = i & 31;
            float f0 = tile[2 * pr][row];
            float f1 = tile[2 * pr + 1][row];
            unsigned pack = (unsigned)f2bf(f0) | ((unsigned)f2bf(f1) << 16);
            reinterpret_cast<unsigned*>(d)[(((long)(c0 + row) * R + r0) >> 1) + pr] = pack;
        }
    } else {
        __shared__ float Vl[32][32];
        __shared__ float fml[32][256];
        int i = x - 1056;
        int b = i >> 4, p0 = (i & 15) * 256;
        #pragma unroll
        for (int j = 0; j < 4; ++j) { int ii = t + 256 * j; Vl[ii >> 5][ii & 31] = V[ii]; }
        for (int j = 0; j < 32; ++j) {
            int ii = t + 256 * j;
            int dd = ii >> 8, c = ii & 255;
            fml[dd][c] = fm[((long)b * DVc + dd) * NP + p0 + c];
        }
        __syncthreads();
        float acc[32];
        #pragma unroll
        for (int e = 0; e < 32; ++e) acc[e] = 0.f;
        for (int dd = 0; dd < 32; ++dd) {
            float fv = fml[dd][t];
            #pragma unroll
            for (int e = 0; e < 32; ++e) acc[e] += fv * Vl[dd][e];
        }
        #pragma unroll
        for (int e = 0; e < 32; ++e) vproj[((long)b * DVc + e) * NP + p0 + t] = acc[e];
    }
}

// ---------------- k_proj: full-e (256) per 32-p tile. grid (128, 8=b*mat) = 1024 blocks ----------------
// 4 blocks/CU (was 2) for latency hiding; outputs fp32 [b][e][p].
__global__ __launch_bounds__(256) void k_proj(
    const unsigned short* __restrict__ WTq, const unsigned short* __restrict__ WTk,
    const unsigned short* __restrict__ fcT,
    float* __restrict__ qproj, float* __restrict__ kproj) {
    int t = threadIdx.x;
    int wave = t >> 6, lane = t & 63;
    int y = blockIdx.y;
    int b = y & 3, mat = y >> 2;
    int p0 = blockIdx.x * 32;
    int ln = lane & 15, quad = lane >> 4;
    const unsigned short* WT = mat ? WTk : WTq;
    float* dst = mat ? kproj : qproj;
    int e0w = wave * 64;
    const unsigned short* bbase = fcT + ((long)b * NP + p0 + ln) * DKc + quad * 8;
    f32x4 acc[4][2] = {};
    for (int kk = 0; kk < DKc; kk += 32) {
        bf16x8 a[4], bb[2];
        #pragma unroll
        for (int i = 0; i < 4; ++i)
            a[i] = *reinterpret_cast<const bf16x8*>(WT + (long)(e0w + i * 16 + ln) * DKc + quad * 8 + kk);
        #pragma unroll
        for (int j = 0; j < 2; ++j)
            bb[j] = *reinterpret_cast<const bf16x8*>(bbase + (long)j * 16 * DKc + kk);
        #pragma unroll
        for (int i = 0; i < 4; ++i)
            #pragma unroll
            for (int j = 0; j < 2; ++j)
                acc[i][j] = __builtin_amdgcn_mfma_f32_16x16x32_bf16(a[i], bb[j], acc[i][j], 0, 0, 0);
    }
    #pragma unroll
    for (int i = 0; i < 4; ++i)
        #pragma unroll
        for (int j = 0; j < 2; ++j)
            #pragma unroll
            for (int r = 0; r < 4; ++r) {
                int e = e0w + i * 16 + quad * 4 + r, p = p0 + j * 16 + ln;
                dst[((long)b * DKc + e) * NP + p] = acc[i][j][r];
            }
}

// ---------------- k_fused: scores + softmax(w) + ctx + epilogue, one pass ----------------
// grid 256 (b*64+hrow), 1024 thr (16 waves).
// All global streams are 16 B/lane (f32x4): lane=(sub, wg) with wg=lane&15 owning
// a 4-wide w slice. Phase 2: wave=(eh,mq) -> e-half x m-quad; 16 KB partials
// combined in LDS (aliased over the dead q tile). Phase 3: wave=(mh,dq).
// Single 64 KiB LDS buffer (exactly the per-WG limit), 5 uniform barriers.
// 4 b-siblings (64 apart -> same XCD) share the k/v stream via per-XCD L2.
__global__ __launch_bounds__(1024) void k_fused(
    const float* __restrict__ qproj, const float* __restrict__ kproj,
    const float* __restrict__ kbuf, const float* __restrict__ vproj,
    const float* __restrict__ vbuf, const float* __restrict__ fm,
    float* __restrict__ out, float scale) {
    __shared__ float smem[16384];              // 65536 B
    int t = threadIdx.x;
    int b = blockIdx.x >> 6, hrow = blockIdx.x & 63;
    int p0 = hrow * 64;
    int wave = t >> 6, lane = t & 63;
    int wg = lane & 15;

    // phase 1: stage q[b][e][p0..p0+63] -> smem[e*64 + w], f32x4 per lane
    {
        const float* qbase = qproj + (long)b * DKc * NP + p0;
        #pragma unroll
        for (int j = 0; j < 4; ++j) {
            int i = t + 1024 * j;              // [0,4096)
            int e = i >> 4, g = i & 15;
            *reinterpret_cast<f32x4*>(&smem[e * 64 + g * 4]) =
                *reinterpret_cast<const f32x4*>(qbase + (long)e * NP + g * 4);
        }
    }
    __syncthreads();

    // phase 2: scores. wave=(eh= wave>>3, mq= wave&7); lane=(mi=lane>>4, wg).
    // m = mq*4+mi (mq==0 -> all m<4: kproj, else kbuf). e in [eh*128, eh*128+128).
    {
        int mi = lane >> 4;
        int eh = wave >> 3, mq = wave & 7;
        int m = mq * 4 + mi;
        const float* kbase = (mq == 0 ? kproj + (long)m * DKc * NP
                                      : kbuf + (long)(m - 4) * DKc * NP)
                             + (long)(eh * 128) * NP + p0 + wg * 4;
        const float* qb = &smem[(eh * 128) * 64 + wg * 4];
        f32x4 s4 = {0.f, 0.f, 0.f, 0.f};
        for (int e8 = 0; e8 < 128; e8 += 8) {
            f32x4 kv[8], qv[8];
            #pragma unroll
            for (int u = 0; u < 8; ++u)
                kv[u] = *reinterpret_cast<const f32x4*>(kbase + (long)(e8 + u) * NP);
            #pragma unroll
            for (int u = 0; u < 8; ++u)
                qv[u] = *reinterpret_cast<const f32x4*>(qb + (e8 + u) * 64);
            #pragma unroll
            for (int u = 0; u < 8; ++u)
                s4 += qv[u] * kv[u];
        }
        __syncthreads();                       // all q reads retired -> region reusable
        // partial scores: smem[eh*2048 + m*64 + w]
        *reinterpret_cast<f32x4*>(&smem[eh * 2048 + m * 64 + wg * 4]) = s4;
    }
    __syncthreads();

    // softmax over w: wave handles 2 m rows; lane = w. attn -> smem[4096 + m*64 + w]
    #pragma unroll
    for (int r = 0; r < 2; ++r) {
        int m = wave * 2 + r;
        float x = (smem[m * 64 + lane] + smem[2048 + m * 64 + lane]) * scale;
        float mx = x;
        #pragma unroll
        for (int dd = 1; dd < 64; dd <<= 1) mx = fmaxf(mx, __shfl_xor(mx, dd));
        float ev = __expf(x - mx);
        float sum = ev;
        #pragma unroll
        for (int dd = 1; dd < 64; dd <<= 1) sum += __shfl_xor(sum, dd);
        smem[4096 + m * 64 + lane] = ev / sum;
    }
    __syncthreads();

    // phase 3: ctx. wave=(mh= wave>>3, dq= wave&7); lane=(di=lane>>4, wg).
    // d = dq*4+di; accumulate over m in [mh*16, mh*16+16). v loads f32x4.
    {
        int di = lane >> 4;
        int mh = wave >> 3, dq = wave & 7;
        int dd = dq * 4 + di;
        f32x4 c4 = {0.f, 0.f, 0.f, 0.f};
        #pragma unroll
        for (int mm = 0; mm < 16; ++mm) {
            int m = mh * 16 + mm;
            const float* vb_ = (m < 4 ? vproj + (long)m * DVc * NP
                                      : vbuf + (long)(m - 4) * DVc * NP);
            f32x4 a4 = *reinterpret_cast<const f32x4*>(&smem[4096 + m * 64 + wg * 4]);
            f32x4 v4 = *reinterpret_cast<const f32x4*>(vb_ + (long)dd * NP + p0 + wg * 4);
            c4 += a4 * v4;
        }
        // ctx partial: smem[mh*2048 + d*64 + w] (partials region is dead)
        *reinterpret_cast<f32x4*>(&smem[mh * 2048 + dd * 64 + wg * 4]) = c4;
    }
    __syncthreads();

    // final: 2048 outputs / 1024 threads
    #pragma unroll
    for (int r = 0; r < 2; ++r) {
        int i = t + 1024 * r;
        int dd = i >> 6, w = i & 63;
        float c = smem[dd * 64 + w] + smem[2048 + dd * 64 + w];
        long gi = ((long)b * DVc + dd) * NP + p0 + w;
        out[gi] = fm[gi] + 0.5f * c;
    }
}

extern "C" void kernel_launch(void* const* d_in, const int* in_sizes, int n_in,
                              void* d_out, int out_size, void* d_ws, size_t ws_size,
                              hipStream_t stream) {
    const float* fc = (const float*)d_in[0];
    const float* fm = (const float*)d_in[1];
    const float* kb = (const float*)d_in[2];
    const float* vb = (const float*)d_in[3];
    const float* Q  = (const float*)d_in[4];
    const float* K  = (const float*)d_in[5];
    const float* V  = (const float*)d_in[6];
    float* out = (float*)d_out;
    char* ws = (char*)d_ws;
    // layout: qproj/kproj/vproj persistent; fcT+WT dead after k_proj.
    float*          qproj = (float*)(ws);                          // 16777216 B
    float*          kproj = (float*)(ws + 16777216);               // 16777216 B
    float*          vproj = (float*)(ws + 33554432);               //  2097152 B
    unsigned short* fcT   = (unsigned short*)(ws + 35651584);      //  8388608 B
    unsigned short* WTq   = (unsigned short*)(ws + 44040192);      //   131072 B
    unsigned short* WTk   = (unsigned short*)(ws + 44171264);      //   131072 B
    float scale = (float)(log(135168.0) / log(1000.0) / 16.0);

    hipLaunchKernelGGL(k_prep, dim3(1120), dim3(256), 0, stream,
                       fc, fcT, Q, WTq, K, WTk, fm, V, vproj);
    hipLaunchKernelGGL(k_proj, dim3(128, 8), dim3(256), 0, stream,
                       WTq, WTk, fcT, qproj, kproj);
    hipLaunchKernelGGL(k_fused, dim3(256), dim3(1024), 0, stream,
                       qproj, kproj, kb, vproj, vb, fm, out, scale);
}